// Round 5
// baseline (166.367 us; speedup 1.0000x reference)
//
#include <hip/hip_runtime.h>
#include <hip/hip_bf16.h>
#include <math.h>

typedef __bf16 bf16x8 __attribute__((ext_vector_type(8)));
typedef float f32x4 __attribute__((ext_vector_type(4)));

__device__ __forceinline__ unsigned short f2bf(float x) {
    union { float f; unsigned int u; } v; v.f = x;
    unsigned int r = v.u + 0x7fffu + ((v.u >> 16) & 1u);  // round-to-nearest-even
    return (unsigned short)(r >> 16);
}
__device__ __forceinline__ float gelu_exact(float v) {
    return 0.5f * v * (1.0f + erff(v * 0.70710678118654752f));
}

// ---------------------------------------------------------------------------
// prep: blocks [0,4096)   -> span pooling into hp (4096 x 3072 bf16)
//       blocks [4096,4864)-> W1 fp32 -> bf16 (256x3072)
//       blocks [4864,5888)-> zero xacc1 (4096x256 fp32)
// ---------------------------------------------------------------------------
__global__ __launch_bounds__(256) void prep_kernel(const float* __restrict__ hs,
                                                   const int* __restrict__ spans,
                                                   const float* __restrict__ W1,
                                                   unsigned short* __restrict__ hp,
                                                   unsigned short* __restrict__ w1b,
                                                   float* __restrict__ xacc1) {
    const int blk = blockIdx.x;
    const int tid = threadIdx.x;

    if (blk >= 4096) {
        if (blk < 4864) {                     // W1 convert: 196608 float4s
            const int i = (blk - 4096) * 256 + tid;
            float4 f = ((const float4*)W1)[i];
            ushort4 u;
            u.x = f2bf(f.x); u.y = f2bf(f.y); u.z = f2bf(f.z); u.w = f2bf(f.w);
            ((ushort4*)w1b)[i] = u;
        } else {                              // zero xacc1: 262144 float4s
            const int i = (blk - 4864) * 256 + tid;
            ((float4*)xacc1)[i] = make_float4(0.f, 0.f, 0.f, 0.f);
        }
        return;
    }

    const int pair = blk;                     // b*Q + q, Q=128
    const int b = pair >> 7;

    // dtype probe: int64 spans -> word 1 is high half of asp_s[0] (== 0);
    // int32 spans -> it's asp_e[0] which is always >= 2.
    const bool is64 = (spans[1] == 0);
    int s_a, e_a, s_o, e_o;
    if (is64) {
        s_a = spans[(pair * 4 + 0) * 2]; e_a = spans[(pair * 4 + 1) * 2];
        s_o = spans[(pair * 4 + 2) * 2]; e_o = spans[(pair * 4 + 3) * 2];
    } else {
        s_a = spans[pair * 4 + 0]; e_a = spans[pair * 4 + 1];
        s_o = spans[pair * 4 + 2]; e_o = spans[pair * 4 + 3];
    }

    const float4* base = (const float4*)hs + (size_t)b * 512 * 256;  // L=512, H/4=256

    float4 A, O;
    if (s_a >= 2 && e_a >= s_a) {
        float sx = 0.f, sy = 0.f, sz = 0.f, sw = 0.f;
        for (int t = s_a; t <= e_a; ++t) {
            float4 v = base[t * 256 + tid];
            sx += v.x; sy += v.y; sz += v.z; sw += v.w;
        }
        float inv = 1.0f / (float)(e_a - s_a + 1);
        A.x = sx * inv; A.y = sy * inv; A.z = sz * inv; A.w = sw * inv;
    } else {
        A = base[256 + tid];                  // sep token, row 1
    }
    if (s_o >= 2 && e_o >= s_o) {
        float sx = 0.f, sy = 0.f, sz = 0.f, sw = 0.f;
        for (int t = s_o; t <= e_o; ++t) {
            float4 v = base[t * 256 + tid];
            sx += v.x; sy += v.y; sz += v.z; sw += v.w;
        }
        float inv = 1.0f / (float)(e_o - s_o + 1);
        O.x = sx * inv; O.y = sy * inv; O.z = sz * inv; O.w = sw * inv;
    } else {
        O = base[256 + tid];
    }

    unsigned short* row = hp + (size_t)pair * 3072;
    const int d = tid * 4;
    ushort4 pa, po, pp;
    pa.x = f2bf(A.x); pa.y = f2bf(A.y); pa.z = f2bf(A.z); pa.w = f2bf(A.w);
    po.x = f2bf(O.x); po.y = f2bf(O.y); po.z = f2bf(O.z); po.w = f2bf(O.w);
    pp.x = f2bf(A.x * O.x); pp.y = f2bf(A.y * O.y);
    pp.z = f2bf(A.z * O.z); pp.w = f2bf(A.w * O.w);
    *(ushort4*)(row + d) = pa;
    *(ushort4*)(row + 1024 + d) = po;
    *(ushort4*)(row + 2048 + d) = pp;
}

// ---------------------------------------------------------------------------
// GEMM1 (m97-style): xacc += A @ Bw^T, split-K atomics.
// A: 4096 x 3072 bf16 (hp). Bw: 256 x 3072 bf16 (w1b). N fixed = 256.
// BM=BN=128, BK=64, S=8 (Ks=384, 6 iters). grid (32, 2, 8) = 512 blocks.
// 4 waves 2x2, wave tile 64x64 = 4x4 x mfma_16x16x32_bf16.
// Staging via global_load_lds width=16 with XOR chunk swizzle:
//   LDS slot s -> row=s>>3, pchunk=s&7 holds global chunk pchunk^(row&7).
//   ds_read side XORs the same way -> uniform bank load (no conflicts).
// K-advance folded into the global pointer (offset arg must be ICE 0).
// ---------------------------------------------------------------------------
__global__ __launch_bounds__(256, 2) void gemm1_mfma(const unsigned short* __restrict__ A,
                                                     const unsigned short* __restrict__ Bw,
                                                     float* __restrict__ xacc) {
    __shared__ __align__(16) unsigned short As[128 * 64];
    __shared__ __align__(16) unsigned short Bs[128 * 64];

    const int tid = threadIdx.x;
    const int lane = tid & 63;
    const int wid = tid >> 6;
    const int quad = lane >> 4;
    const int l16 = lane & 15;
    const int wM = (wid >> 1) * 64;
    const int wN = (wid & 1) * 64;
    const int m0 = blockIdx.x * 128;
    const int n0 = blockIdx.y * 128;
    const int kb = blockIdx.z * 384;

    // staging source: slot (j*256+tid) -> row = j*32 + (tid>>3), pchunk = tid&7
    const int srow = tid >> 3;
    const int lchunk = (tid & 7) ^ (srow & 7);
    const unsigned short* Abase = A + (size_t)(m0 + srow) * 3072 + kb + lchunk * 8;
    const unsigned short* Bbase = Bw + (size_t)(n0 + srow) * 3072 + kb + lchunk * 8;

    // fragment LDS offsets (halfwords), fixed across iters
    int aoff[4][2], boff[4][2];
#pragma unroll
    for (int mi = 0; mi < 4; ++mi) {
#pragma unroll
        for (int h = 0; h < 2; ++h) {
            int row = wM + mi * 16 + l16;
            int pc = (h * 4 + quad) ^ (row & 7);
            aoff[mi][h] = row * 64 + pc * 8;
            row = wN + mi * 16 + l16;
            pc = (h * 4 + quad) ^ (row & 7);
            boff[mi][h] = row * 64 + pc * 8;
        }
    }

    f32x4 acc[4][4] = {};

#pragma unroll
    for (int it = 0; it < 6; ++it) {
        const int kadv = it * 64;             // halfwords along K
#pragma unroll
        for (int j = 0; j < 4; ++j) {
            __builtin_amdgcn_global_load_lds(
                (const __attribute__((address_space(1))) void*)(Abase + (size_t)j * 32 * 3072 + kadv),
                (__attribute__((address_space(3))) void*)(&As[(j * 256 + tid) * 8]),
                16, 0, 0);
            __builtin_amdgcn_global_load_lds(
                (const __attribute__((address_space(1))) void*)(Bbase + (size_t)j * 32 * 3072 + kadv),
                (__attribute__((address_space(3))) void*)(&Bs[(j * 256 + tid) * 8]),
                16, 0, 0);
        }
        __syncthreads();
#pragma unroll
        for (int h = 0; h < 2; ++h) {
            bf16x8 af[4], bfr[4];
#pragma unroll
            for (int mi = 0; mi < 4; ++mi) af[mi] = *(const bf16x8*)&As[aoff[mi][h]];
#pragma unroll
            for (int ni = 0; ni < 4; ++ni) bfr[ni] = *(const bf16x8*)&Bs[boff[ni][h]];
#pragma unroll
            for (int mi = 0; mi < 4; ++mi)
#pragma unroll
                for (int ni = 0; ni < 4; ++ni)
                    acc[mi][ni] = __builtin_amdgcn_mfma_f32_16x16x32_bf16(
                        af[mi], bfr[ni], acc[mi][ni], 0, 0, 0);
        }
        __syncthreads();
    }

#pragma unroll
    for (int mi = 0; mi < 4; ++mi) {
#pragma unroll
        for (int ni = 0; ni < 4; ++ni) {
            const int n = n0 + wN + ni * 16 + l16;
#pragma unroll
            for (int rr = 0; rr < 4; ++rr) {
                const int m = m0 + wM + mi * 16 + quad * 4 + rr;
                unsafeAtomicAdd(&xacc[(size_t)m * 256 + n], acc[mi][ni][rr]);
            }
        }
    }
}

// ---------------------------------------------------------------------------
// bias + exact GELU: x1 = gelu(xacc + b1) -> bf16.
// ---------------------------------------------------------------------------
__global__ __launch_bounds__(256) void gelu_bias(const float* __restrict__ xacc,
                                                 const float* __restrict__ bias,
                                                 unsigned short* __restrict__ xout,
                                                 int total4, int ncols4) {
    for (int i = blockIdx.x * blockDim.x + threadIdx.x; i < total4;
         i += gridDim.x * blockDim.x) {
        float4 v = ((const float4*)xacc)[i];
        float4 bv = ((const float4*)bias)[i & (ncols4 - 1)];
        ushort4 u;
        u.x = f2bf(gelu_exact(v.x + bv.x));
        u.y = f2bf(gelu_exact(v.y + bv.y));
        u.z = f2bf(gelu_exact(v.z + bv.z));
        u.w = f2bf(gelu_exact(v.w + bv.w));
        ((ushort4*)xout)[i] = u;
    }
}

// ---------------------------------------------------------------------------
// Fused GEMM2 + bias + GELU + head: 32 pairs/block, grid 128.
// ---------------------------------------------------------------------------
__global__ __launch_bounds__(256) void mlp2_head(const unsigned short* __restrict__ x1,
                                                 const float* __restrict__ W2f,
                                                 const float* __restrict__ b2,
                                                 const float* __restrict__ W3,
                                                 const float* __restrict__ b3,
                                                 const float* __restrict__ mask,
                                                 float* __restrict__ out) {
    __shared__ __align__(16) unsigned short Xs[32][72];
    __shared__ __align__(16) unsigned short Ws[128][72];
    __shared__ float X2[32][132];

    const int tid = threadIdx.x;
    const int lane = tid & 63;
    const int wid = tid >> 6;
    const int wM = (wid >> 1) * 16;   // waves 2x2: wave tile 16 x 64
    const int wN = (wid & 1) * 64;
    const int quad = lane >> 4;
    const int l16 = lane & 15;
    const int m0 = blockIdx.x * 32;

    f32x4 acc[4] = {};

    for (int k0 = 0; k0 < 256; k0 += 64) {
        {   // stage Xs 32x64 bf16
            const int r = tid >> 3, c = (tid & 7) * 8;
            *(uint4*)&Xs[r][c] = *(const uint4*)(x1 + (size_t)(m0 + r) * 256 + k0 + c);
        }
#pragma unroll
        for (int p = 0; p < 4; ++p) {   // stage Ws 128x64 from fp32
            const int v = tid + p * 256;
            const int r = v >> 3, c = (v & 7) * 8;
            const float* src = W2f + (size_t)r * 256 + k0 + c;
            float4 f0 = *(const float4*)src;
            float4 f1 = *(const float4*)(src + 4);
            ushort4 u;
            u.x = f2bf(f0.x); u.y = f2bf(f0.y); u.z = f2bf(f0.z); u.w = f2bf(f0.w);
            *(ushort4*)&Ws[r][c] = u;
            u.x = f2bf(f1.x); u.y = f2bf(f1.y); u.z = f2bf(f1.z); u.w = f2bf(f1.w);
            *(ushort4*)&Ws[r][c + 4] = u;
        }
        __syncthreads();
#pragma unroll
        for (int kk = 0; kk < 64; kk += 32) {
            bf16x8 a = *(const bf16x8*)&Xs[wM + l16][kk + quad * 8];
#pragma unroll
            for (int ni = 0; ni < 4; ++ni) {
                bf16x8 b = *(const bf16x8*)&Ws[wN + ni * 16 + l16][kk + quad * 8];
                acc[ni] = __builtin_amdgcn_mfma_f32_16x16x32_bf16(a, b, acc[ni], 0, 0, 0);
            }
        }
        __syncthreads();
    }

#pragma unroll
    for (int ni = 0; ni < 4; ++ni) {
        const int n = wN + ni * 16 + l16;
        const float bn = b2[n];
#pragma unroll
        for (int rr = 0; rr < 4; ++rr) {
            const int m = wM + quad * 4 + rr;
            X2[m][n] = gelu_exact(acc[ni][rr] + bn);
        }
    }
    __syncthreads();

    const int p = tid >> 3;           // pair-in-block 0..31
    const int cc = (tid & 7) * 16;
    float a0 = 0.f, a1 = 0.f;
#pragma unroll
    for (int j = 0; j < 16; ++j) {
        const float xv = X2[p][cc + j];
        a0 += xv * W3[cc + j];
        a1 += xv * W3[128 + cc + j];
    }
    a0 += __shfl_xor(a0, 1); a0 += __shfl_xor(a0, 2); a0 += __shfl_xor(a0, 4);
    a1 += __shfl_xor(a1, 1); a1 += __shfl_xor(a1, 2); a1 += __shfl_xor(a1, 4);
    if ((tid & 7) == 0) {
        const int pair = m0 + p;
        const float mk = (mask[pair] >= 0.5f) ? 1.0f : 0.0f;
        out[pair * 2 + 0] = ((1.0f / (1.0f + expf(-(a0 + b3[0])))) * 8.0f + 1.0f) * mk;
        out[pair * 2 + 1] = ((1.0f / (1.0f + expf(-(a1 + b3[1])))) * 8.0f + 1.0f) * mk;
    }
}

// ---------------------------------------------------------------------------
extern "C" void kernel_launch(void* const* d_in, const int* in_sizes, int n_in,
                              void* d_out, int out_size, void* d_ws, size_t ws_size,
                              hipStream_t stream) {
    const float* hs   = (const float*)d_in[0];
    const int*   spans= (const int*)d_in[1];
    const float* mask = (const float*)d_in[2];
    const float* W1   = (const float*)d_in[3];
    const float* b1   = (const float*)d_in[4];
    const float* W2   = (const float*)d_in[5];
    const float* b2   = (const float*)d_in[6];
    const float* W3   = (const float*)d_in[7];
    const float* b3   = (const float*)d_in[8];
    float* out = (float*)d_out;

    // ws: hp bf16 4096x3072 [0, 25165824); xacc1 fp32 4096x256 [25165824, +4MB);
    // w1b bf16 256x3072 [29360128, +1.5MB). x1 (bf16 4096x256, 2MB) aliases hp.
    unsigned short* hp    = (unsigned short*)d_ws;
    float*          xacc1 = (float*)((char*)d_ws + 25165824);
    unsigned short* w1b   = (unsigned short*)((char*)d_ws + 29360128);
    unsigned short* x1    = (unsigned short*)d_ws;

    prep_kernel<<<dim3(5888), dim3(256), 0, stream>>>(hs, spans, W1, hp, w1b, xacc1);
    gemm1_mfma<<<dim3(32, 2, 8), dim3(256), 0, stream>>>(hp, w1b, xacc1);
    gelu_bias<<<dim3(512), dim3(256), 0, stream>>>(xacc1, b1, x1, 4096 * 256 / 4, 64);
    mlp2_head<<<dim3(128), dim3(256), 0, stream>>>(x1, W2, b2, W3, b3, mask, out);
}